// Round 11
// baseline (2195.983 us; speedup 1.0000x reference)
//
#include <hip/hip_runtime.h>
#include <hip/hip_bf16.h>
#include <hip/hip_fp8.h>
#include <stdint.h>

#define D_MODEL 1024
#define VOCAB 50257
#define VP 51200          // padded vocab
#define ROWS 4096
#define LN_EPS 1e-5f

typedef int   i32x4 __attribute__((ext_vector_type(4)));
typedef int   i32x8 __attribute__((ext_vector_type(8)));
typedef float f32x4 __attribute__((ext_vector_type(4)));

#define SCALE1 0x7F7F7F7F   // e8m0 127 = 1.0 in every byte lane

__device__ __forceinline__ unsigned char f2f8(float f) {
  __hip_fp8_e4m3 h(f);                       // OCP e4m3fn on gfx950
  return *reinterpret_cast<unsigned char*>(&h);
}
// arithmetic e4m3fn decode (P >= 0, no NaN stored)
__device__ __forceinline__ float f8dec(uint32_t u) {
  const uint32_t e = (u >> 3) & 0xF, m = u & 7;
  const int ex = e ? (int)e - 10 : -9;
  const float mm = (float)(e ? 8 + m : m);
  return ldexpf(mm, ex);
}
__device__ __forceinline__ void gload_lds16(const void* g, void* l) {
  __builtin_amdgcn_global_load_lds(
      (const __attribute__((address_space(1))) unsigned int*)g,
      (__attribute__((address_space(3))) unsigned int*)l, 16, 0, 0);
}

// ---- generic fp32 -> fp8 cast (elements >= nvalid zeroed) ----
__global__ __launch_bounds__(256) void k_f32_to_f8(const float* __restrict__ src,
                                                   unsigned char* __restrict__ dst,
                                                   long long nvalid) {
  const long long i0 = ((long long)blockIdx.x * 256 + threadIdx.x) * 16;
  uint32_t wv[4];
  #pragma unroll
  for (int wi = 0; wi < 4; ++wi) {
    const long long base = i0 + wi * 4;
    uint32_t x = 0;
    if (base + 4 <= nvalid) {
      const f32x4 a = *reinterpret_cast<const f32x4*>(src + base);
      x = (uint32_t)f2f8(a[0]) | ((uint32_t)f2f8(a[1]) << 8)
        | ((uint32_t)f2f8(a[2]) << 16) | ((uint32_t)f2f8(a[3]) << 24);
    } else if (base < nvalid) {
      #pragma unroll
      for (int j = 0; j < 4; ++j) {
        const long long idx = base + j;
        const float v = (idx < nvalid) ? src[idx] : 0.f;
        x |= (uint32_t)f2f8(v) << (8 * j);
      }
    }
    wv[wi] = x;
  }
  i32x4 o = { (int)wv[0], (int)wv[1], (int)wv[2], (int)wv[3] };
  *reinterpret_cast<i32x4*>(dst + i0) = o;
}

// ---- emb [VOCAB][1024] fp32 -> ET fp8 [1024][VP] (transpose, zero-pad) ----
__global__ __launch_bounds__(256) void k_packet8(const float* __restrict__ emb,
                                                 unsigned char* __restrict__ et) {
  __shared__ float tile[32][33];
  const int v0 = blockIdx.x * 32;
  const int d0 = blockIdx.y * 32;
  const int tx = threadIdx.x, ty = threadIdx.y;  // 32 x 8
  #pragma unroll
  for (int i = 0; i < 4; ++i) {
    const int v = v0 + ty + 8 * i;
    tile[ty + 8 * i][tx] = (v < VOCAB) ? emb[(size_t)v * D_MODEL + d0 + tx] : 0.f;
  }
  __syncthreads();
  #pragma unroll
  for (int i = 0; i < 4; ++i) {
    const int d = d0 + ty + 8 * i;
    et[(size_t)d * VP + v0 + tx] = f2f8(tile[tx][ty + 8 * i]);
  }
}

// ---- GEMM1: P = exp(enc.W^T + b), A-resident in LDS, MX-fp8 K=128 ----
// 256 blocks = 32 q-tiles x 8 v-splits (v-split == XCD). Per block:
// A tile (128q x 1024K fp8, 128 KB) staged ONCE; loop 50 v-tiles x 8 kt,
// B (128v x 128K, 16 KB) double-buffered, T3-min schedule (1 barrier/phase).
// 8 waves as 4m x 2n, wave 32q x 64v. acc 32 + bf 32 + af 8 regs, cap 256.
__global__ __launch_bounds__(512, 2)
void k_gemm1(const unsigned char* __restrict__ A8,   // enc fp8 [4096][1024]
             const unsigned char* __restrict__ B8,   // W fp8 [VP][1024]
             const float* __restrict__ bias,
             unsigned char* __restrict__ P) {        // [4096][VP] fp8
  __shared__ __align__(16) unsigned char As[131072];   // [kt][128r][128B swz]
  __shared__ __align__(16) unsigned char Bs[2][16384]; // dbuf B / P-out tile

  const int bx = blockIdx.x;
  const int vs = bx & 7;                 // v-split == XCD slot
  const int row0 = (bx >> 3) * 128;      // q-tile
  const int vsbase = vs * 6400;

  const int tid = threadIdx.x;
  const int w = tid >> 6, l = tid & 63;
  const int mw = w >> 1, nw = w & 1;     // 4m x 2n
  const int r16 = l & 15, g = l >> 4;

  // ---- stage full A tile (8192 x 16B chunks, swizzled) ----
  #pragma unroll
  for (int ii = 0; ii < 16; ++ii) {
    const int d = tid + ii * 512;
    const int kt = d >> 10;
    const int rc = d & 1023;
    const int r = rc >> 3, sc = rc & 7;
    gload_lds16(A8 + (size_t)(row0 + r) * 1024 + kt * 128 + (sc ^ (r & 7)) * 16,
                &As[d * 16]);
  }
  // ---- stage B phase 0 ----
  #pragma unroll
  for (int ii = 0; ii < 2; ++ii) {
    const int d = tid + ii * 512;
    const int r = d >> 3, sc = d & 7;
    gload_lds16(B8 + (size_t)(vsbase + r) * 1024 + (sc ^ (r & 7)) * 16,
                &Bs[0][d * 16]);
  }
  __syncthreads();

  const uint32_t sw = (uint32_t)(r16 & 7) << 4;
  const uint32_t o0 = ((uint32_t)g * 32) ^ sw;
  const uint32_t o1 = ((uint32_t)g * 32 + 16) ^ sw;
  const uint32_t abase = (uint32_t)(mw * 32 + r16) * 128;
  const uint32_t bbase = (uint32_t)(nw * 64 + r16) * 128;

  int cur = 0;
  for (int nt = 0; nt < 50; ++nt) {
    const int v0 = vsbase + nt * 128;
    float bv[4];
    #pragma unroll
    for (int b = 0; b < 4; ++b) {
      const int v = v0 + nw * 64 + b * 16 + r16;
      bv[b] = (v < VOCAB) ? bias[v] : 0.f;
    }
    f32x4 acc[2][4];
    #pragma unroll
    for (int a = 0; a < 2; ++a)
      #pragma unroll
      for (int b = 0; b < 4; ++b) acc[a][b] = f32x4{0.f, 0.f, 0.f, 0.f};

    for (int kt = 0; kt < 8; ++kt) {
      // issue next-phase B stage (latency hides under this phase's compute)
      const int pn = nt * 8 + kt + 1;
      if (pn < 400) {
        const int vn = vsbase + (pn >> 3) * 128;
        const int ktn = pn & 7;
        #pragma unroll
        for (int ii = 0; ii < 2; ++ii) {
          const int d = tid + ii * 512;
          const int r = d >> 3, sc = d & 7;
          gload_lds16(B8 + (size_t)(vn + r) * 1024 + ktn * 128 + (sc ^ (r & 7)) * 16,
                      &Bs[cur ^ 1][d * 16]);
        }
      }
      // compute from As[kt] and Bs[cur]
      const unsigned char* Ak = As + kt * 16384;
      const unsigned char* Bk = Bs[cur];
      i32x8 bf[4];
      #pragma unroll
      for (int b = 0; b < 4; ++b) {
        const i32x4 lo = *reinterpret_cast<const i32x4*>(Bk + bbase + b * 2048 + o0);
        const i32x4 hi = *reinterpret_cast<const i32x4*>(Bk + bbase + b * 2048 + o1);
        bf[b] = i32x8{lo[0], lo[1], lo[2], lo[3], hi[0], hi[1], hi[2], hi[3]};
      }
      #pragma unroll
      for (int a = 0; a < 2; ++a) {
        const i32x4 lo = *reinterpret_cast<const i32x4*>(Ak + abase + a * 2048 + o0);
        const i32x4 hi = *reinterpret_cast<const i32x4*>(Ak + abase + a * 2048 + o1);
        const i32x8 af = {lo[0], lo[1], lo[2], lo[3], hi[0], hi[1], hi[2], hi[3]};
        #pragma unroll
        for (int b = 0; b < 4; ++b)
          acc[a][b] = __builtin_amdgcn_mfma_scale_f32_16x16x128_f8f6f4(
              af, bf[b], acc[a][b], 0, 0, 0, SCALE1, 0, SCALE1);
      }
      __syncthreads();   // drains next-phase stage; frees Bs[cur] for overwrite
      cur ^= 1;
    }

    // ---- epilogue: exp -> fp8 into free buffer, then coalesced stores ----
    unsigned char* Pl = Bs[cur ^ 1];   // just-read buffer (free); Bs[cur] holds next tile
    #pragma unroll
    for (int a = 0; a < 2; ++a) {
      #pragma unroll
      for (int j = 0; j < 4; ++j) {
        const int qloc = mw * 32 + a * 16 + g * 4 + j;
        #pragma unroll
        for (int b = 0; b < 4; ++b) {
          const int vloc = nw * 64 + b * 16 + r16;
          const float e = (v0 + vloc < VOCAB) ? __expf(acc[a][b][j] + bv[b]) : 0.f;
          Pl[qloc * 128 + vloc] = f2f8(e);
        }
      }
    }
    __syncthreads();   // P tile complete
    #pragma unroll
    for (int cc = 0; cc < 2; ++cc) {   // 1024 x 16B coalesced
      const int c = tid * 2 + cc;
      const int qloc = c >> 3, vof = (c & 7) * 16;
      const i32x4 val = *reinterpret_cast<const i32x4*>(Pl + qloc * 128 + vof);
      *reinterpret_cast<i32x4*>(P + (size_t)(row0 + qloc) * VP + v0 + vof) = val;
    }
    __syncthreads();   // Pl reads done before next phase stages into it
  }
}

// ---- GEMM2: opart[ks] = P.ET^T slice, MX-fp8 K=128, K-split 8 over VP ----
// 128(q) x 128(d) tile, BK=128, 50 K-steps, 8 waves (4m x 2n), wave 32x64.
__global__ __launch_bounds__(512, 2)
void k_gemm2(const unsigned char* __restrict__ P,
             const unsigned char* __restrict__ ET,
             float* __restrict__ opart) {
  __shared__ __align__(16) unsigned char As[128 * 128];  // 16 KB (P rows)
  __shared__ __align__(16) unsigned char Bs[128 * 128];  // 16 KB (ET rows)

  const int bx = blockIdx.x;
  const int ks = bx & 7, bi = bx >> 3;       // XCD owns one K-split; bi in [0,256)
  const int mt_ = bi & 31, nd = bi >> 5;     // q-tile 0..31, d-tile 0..7
  const int row0 = mt_ * 128, col0 = nd * 128;
  const int k0 = ks * (VP / 8);              // 6400

  const int tid = threadIdx.x;
  const int w = tid >> 6, l = tid & 63;
  const int mw = w >> 1, nw = w & 1;         // 4m x 2n
  const int r16 = l & 15, g = l >> 4;

  f32x4 acc[2][4];
  #pragma unroll
  for (int a = 0; a < 2; ++a)
    #pragma unroll
    for (int b = 0; b < 4; ++b) acc[a][b] = f32x4{0.f, 0.f, 0.f, 0.f};

  const uint32_t sw = (uint32_t)(r16 & 7) << 4;
  const uint32_t o0 = ((uint32_t)g * 32) ^ sw;
  const uint32_t o1 = ((uint32_t)g * 32 + 16) ^ sw;
  const uint32_t abase = (uint32_t)(mw * 32 + r16) * 128;
  const uint32_t bbase = (uint32_t)(nw * 64 + r16) * 128;

  for (int kt = 0; kt < 50; ++kt) {
    const int koff = k0 + kt * 128;
    __syncthreads();
    #pragma unroll
    for (int ii = 0; ii < 2; ++ii) {  // A: 1024 chunks (P rows)
      const int c = tid + ii * 512;
      const int r = c >> 3, s2 = (c & 7) ^ (r & 7);
      gload_lds16(P + (size_t)(row0 + r) * VP + koff + s2 * 16, &As[c * 16]);
    }
    #pragma unroll
    for (int ii = 0; ii < 2; ++ii) {  // B: 1024 chunks (ET rows)
      const int c = tid + ii * 512;
      const int r = c >> 3, s2 = (c & 7) ^ (r & 7);
      gload_lds16(ET + (size_t)(col0 + r) * VP + koff + s2 * 16, &Bs[c * 16]);
    }
    __syncthreads();

    i32x8 bf[4];
    #pragma unroll
    for (int b = 0; b < 4; ++b) {
      const i32x4 lo = *reinterpret_cast<const i32x4*>(Bs + bbase + b * 2048 + o0);
      const i32x4 hi = *reinterpret_cast<const i32x4*>(Bs + bbase + b * 2048 + o1);
      bf[b] = i32x8{lo[0], lo[1], lo[2], lo[3], hi[0], hi[1], hi[2], hi[3]};
    }
    #pragma unroll
    for (int a = 0; a < 2; ++a) {
      const i32x4 lo = *reinterpret_cast<const i32x4*>(As + abase + a * 2048 + o0);
      const i32x4 hi = *reinterpret_cast<const i32x4*>(As + abase + a * 2048 + o1);
      const i32x8 af = {lo[0], lo[1], lo[2], lo[3], hi[0], hi[1], hi[2], hi[3]};
      #pragma unroll
      for (int b = 0; b < 4; ++b)
        acc[a][b] = __builtin_amdgcn_mfma_scale_f32_16x16x128_f8f6f4(
            af, bf[b], acc[a][b], 0, 0, 0, SCALE1, 0, SCALE1);
    }
  }

  // epilogue: plain stores (16-lane-contiguous 64B sectors)
  #pragma unroll
  for (int a = 0; a < 2; ++a) {
    #pragma unroll
    for (int j = 0; j < 4; ++j) {
      const int q = row0 + mw * 32 + a * 16 + g * 4 + j;
      float* orow = opart + ((size_t)ks * ROWS + q) * D_MODEL;
      #pragma unroll
      for (int b = 0; b < 4; ++b) {
        const int d = col0 + nw * 64 + b * 16 + r16;
        orow[d] = acc[a][b][j];
      }
    }
  }
}

// ---- LN epilogue: den from fp8 P row + combine partials + residual + LN ----
__global__ __launch_bounds__(256)
void k_ln2(const float* __restrict__ enc, const float* __restrict__ opart,
           const unsigned char* __restrict__ P, const float* __restrict__ gam,
           const float* __restrict__ bet, float* __restrict__ out) {
  __shared__ float rD[4], r1[4], r2[4];
  const int row = blockIdx.x;
  const int t = threadIdx.x;
  const int d = t * 4;

  // den = sum of the row of fp8 P (self-consistent with GEMM2's numerator)
  float dn = 0.f;
  const uint32_t* prow = reinterpret_cast<const uint32_t*>(P + (size_t)row * VP);
  #pragma unroll 5
  for (int i = 0; i < 50; ++i) {
    const uint32_t x = prow[i * 256 + t];
    dn += f8dec(x & 0xFF) + f8dec((x >> 8) & 0xFF)
        + f8dec((x >> 16) & 0xFF) + f8dec(x >> 24);
  }
  #pragma unroll
  for (int off = 1; off < 64; off <<= 1) dn += __shfl_xor(dn, off);
  if ((t & 63) == 0) rD[t >> 6] = dn;
  __syncthreads();
  const float den = rD[0] + rD[1] + rD[2] + rD[3];
  const float inv = 1.f / den;

  f32x4 acc = {0.f, 0.f, 0.f, 0.f};
  #pragma unroll
  for (int ks = 0; ks < 8; ++ks) {
    const f32x4 a = *reinterpret_cast<const f32x4*>(opart + ((size_t)ks * ROWS + row) * D_MODEL + d);
    #pragma unroll
    for (int jj = 0; jj < 4; ++jj) acc[jj] += a[jj];
  }
  const f32x4 e = *reinterpret_cast<const f32x4*>(enc + (size_t)row * D_MODEL + d);
  f32x4 y;
  #pragma unroll
  for (int jj = 0; jj < 4; ++jj) y[jj] = e[jj] + acc[jj] * inv;
  float s1 = y[0] + y[1] + y[2] + y[3];
  float s2 = y[0]*y[0] + y[1]*y[1] + y[2]*y[2] + y[3]*y[3];
  #pragma unroll
  for (int off = 1; off < 64; off <<= 1) {
    s1 += __shfl_xor(s1, off);
    s2 += __shfl_xor(s2, off);
  }
  if ((t & 63) == 0) { r1[t >> 6] = s1; r2[t >> 6] = s2; }
  __syncthreads();
  const float S1 = r1[0] + r1[1] + r1[2] + r1[3];
  const float S2 = r2[0] + r2[1] + r2[2] + r2[3];
  const float mean = S1 * (1.f / D_MODEL);
  const float var = S2 * (1.f / D_MODEL) - mean * mean;
  const float rs = rsqrtf(var + LN_EPS);
  const f32x4 gv = *reinterpret_cast<const f32x4*>(gam + d);
  const f32x4 bvv = *reinterpret_cast<const f32x4*>(bet + d);
  f32x4 o;
  #pragma unroll
  for (int jj = 0; jj < 4; ++jj) o[jj] = (y[jj] - mean) * rs * gv[jj] + bvv[jj];
  *reinterpret_cast<f32x4*>(out + (size_t)row * D_MODEL + d) = o;
}

// ============================================================================
extern "C" void kernel_launch(void* const* d_in, const int* in_sizes, int n_in,
                              void* d_out, int out_size, void* d_ws, size_t ws_size,
                              hipStream_t stream) {
  const float* enc = (const float*)d_in[0];
  const float* pw  = (const float*)d_in[1];
  const float* pb  = (const float*)d_in[2];
  const float* emb = (const float*)d_in[3];
  const float* gam = (const float*)d_in[4];
  const float* bet = (const float*)d_in[5];
  float* out = (float*)d_out;

  size_t off = 0;
  unsigned char* enc8 = (unsigned char*)((char*)d_ws + off); off += (size_t)ROWS * D_MODEL;          // 4.2 MB
  unsigned char* W8   = (unsigned char*)((char*)d_ws + off); off += (size_t)VP * D_MODEL;            // 52.4 MB
  unsigned char* ET8  = (unsigned char*)((char*)d_ws + off); off += (size_t)D_MODEL * VP;            // 52.4 MB
  unsigned char* P    = (unsigned char*)((char*)d_ws + off); off += (size_t)ROWS * VP;               // 209.7 MB
  float* opart        = (float*)((char*)d_ws + off);          off += (size_t)8 * ROWS * D_MODEL * 4; // 134.2 MB

  if (off > ws_size) {
    // unambiguous sentinel: ws too small -> absmax ~3.4e38
    hipMemsetAsync(d_out, 0x7f, (size_t)out_size * 4, stream);
    return;
  }

  k_f32_to_f8<<<(ROWS * D_MODEL / 16) / 256, 256, 0, stream>>>(enc, enc8, (long long)ROWS * D_MODEL);
  k_f32_to_f8<<<((size_t)VP * D_MODEL / 16) / 256, 256, 0, stream>>>(pw, W8, (long long)VOCAB * D_MODEL);
  k_packet8<<<dim3(VP / 32, D_MODEL / 32), dim3(32, 8), 0, stream>>>(emb, ET8);
  k_gemm1<<<256, 512, 0, stream>>>(enc8, W8, pb, P);
  k_gemm2<<<2048, 512, 0, stream>>>(P, ET8, opart);
  k_ln2<<<ROWS, 256, 0, stream>>>(enc, opart, P, gam, bet, out);
}

// Round 12
// 1161.644 us; speedup vs baseline: 1.8904x; 1.8904x over previous
//
#include <hip/hip_runtime.h>
#include <hip/hip_bf16.h>
#include <stdint.h>

#define D_MODEL 1024
#define VOCAB 50257
#define VP 51200          // padded vocab
#define ROWS 4096
#define LN_EPS 1e-5f

typedef short s16x8 __attribute__((ext_vector_type(8)));
typedef float f32x4 __attribute__((ext_vector_type(4)));

__device__ __forceinline__ unsigned short f2bf(float f) {
  union { __hip_bfloat16 h; unsigned short u; } cv;
  cv.h = __float2bfloat16(f);
  return cv.u;
}
__device__ __forceinline__ void gload_lds16(const void* g, void* l) {
  __builtin_amdgcn_global_load_lds(
      (const __attribute__((address_space(1))) unsigned int*)g,
      (__attribute__((address_space(3))) unsigned int*)l, 16, 0, 0);
}

// ---- enc fp32 -> bf16 [4096][1024] ----
__global__ __launch_bounds__(256) void k_cast_enc(const float* __restrict__ src,
                                                  unsigned short* __restrict__ dst) {
  const size_t i0 = ((size_t)blockIdx.x * 256 + threadIdx.x) * 8;
  const f32x4* p = reinterpret_cast<const f32x4*>(src + i0);
  f32x4 a = p[0], b = p[1];
  s16x8 o;
  o[0]=f2bf(a[0]); o[1]=f2bf(a[1]); o[2]=f2bf(a[2]); o[3]=f2bf(a[3]);
  o[4]=f2bf(b[0]); o[5]=f2bf(b[1]); o[6]=f2bf(b[2]); o[7]=f2bf(b[3]);
  *reinterpret_cast<s16x8*>(dst + i0) = o;
}

// ---- W fp32 [VOCAB][1024] -> bf16 [VP][1024] zero-padded (same layout) ----
__global__ __launch_bounds__(256) void k_pack_wlin(const float* __restrict__ src,
                                                   unsigned short* __restrict__ dst) {
  const size_t i0 = ((size_t)blockIdx.x * 256 + threadIdx.x) * 8;
  const int v = (int)(i0 >> 10);
  s16x8 o;
  if (v < VOCAB) {
    const f32x4* p = reinterpret_cast<const f32x4*>(src + i0);
    f32x4 a = p[0], b = p[1];
    o[0]=f2bf(a[0]); o[1]=f2bf(a[1]); o[2]=f2bf(a[2]); o[3]=f2bf(a[3]);
    o[4]=f2bf(b[0]); o[5]=f2bf(b[1]); o[6]=f2bf(b[2]); o[7]=f2bf(b[3]);
  } else {
    #pragma unroll
    for (int i = 0; i < 8; ++i) o[i] = 0;
  }
  *reinterpret_cast<s16x8*>(dst + i0) = o;
}

// ---- emb [VOCAB][1024] fp32 -> ET bf16 [1024][VP] (transpose, zero-pad) ----
__global__ __launch_bounds__(256) void k_pack_et(const float* __restrict__ emb,
                                                 unsigned short* __restrict__ et) {
  __shared__ float tile[32][33];
  const int v0 = blockIdx.x * 32;
  const int d0 = blockIdx.y * 32;
  const int tx = threadIdx.x, ty = threadIdx.y;  // 32 x 8
  #pragma unroll
  for (int i = 0; i < 4; ++i) {
    const int v = v0 + ty + 8 * i;
    tile[ty + 8 * i][tx] = (v < VOCAB) ? emb[(size_t)v * D_MODEL + d0 + tx] : 0.f;
  }
  __syncthreads();
  #pragma unroll
  for (int i = 0; i < 4; ++i) {
    const int d = d0 + ty + 8 * i;
    et[(size_t)d * VP + v0 + tx] = f2bf(tile[tx][ty + 8 * i]);
  }
}

// ---- GEMM1: P = exp(enc.W^T + b)  [4096 x VP] bf16-out, K=1024 ----
// 128(q) x 256(v) tile, BK=64, 8 waves (2m x 4n), wave 64x64, 16 K-steps.
// Block order: q-tile FAST -> 32 consecutive blocks share one 512 KB W-tile (L2-hit).
__global__ __launch_bounds__(512, 4)
void k_gemm1(const unsigned short* __restrict__ encb,
             const unsigned short* __restrict__ Wb,
             const float* __restrict__ bias,
             unsigned short* __restrict__ P,
             float* __restrict__ den) {
  __shared__ __align__(16) unsigned short As[128 * 64];  // 16 KB swizzled
  __shared__ __align__(16) unsigned short Bs[256 * 64];  // 32 KB swizzled

  const int bx = blockIdx.x;
  const int xcd = bx & 7, bi = bx >> 3;      // bi in [0,800)
  const int mt_ = bi & 31;                   // q-tile FAST (W L2 reuse)
  const int nt_ = xcd * 25 + (bi >> 5);      // v-tile slow, contiguous per XCD
  const int row0 = mt_ * 128;
  const int col0 = nt_ * 256;

  const int tid = threadIdx.x;
  const int w = tid >> 6, l = tid & 63;
  const int mw = w >> 2, nw = w & 3;
  const int r16 = l & 15, g = l >> 4;

  f32x4 acc[4][4];
  #pragma unroll
  for (int a = 0; a < 4; ++a)
    #pragma unroll
    for (int b = 0; b < 4; ++b) acc[a][b] = f32x4{0.f, 0.f, 0.f, 0.f};

  uint32_t arow[4], asw[4], brow[4], bsw[4];
  #pragma unroll
  for (int t = 0; t < 4; ++t) {
    const uint32_t ar = mw * 64 + t * 16 + r16;
    arow[t] = ar * 128; asw[t] = (ar & 7) << 4;
    const uint32_t br = nw * 64 + t * 16 + r16;
    brow[t] = br * 128; bsw[t] = (br & 7) << 4;
  }

  for (int kt = 0; kt < 16; ++kt) {
    __syncthreads();   // prev compute done before overwrite
    #pragma unroll
    for (int ii = 0; ii < 2; ++ii) {  // A: 1024 16B chunks
      const int c = tid + ii * 512;
      const int r = c >> 3, s2 = (c & 7) ^ (r & 7);
      gload_lds16(encb + (size_t)(row0 + r) * 1024 + kt * 64 + s2 * 8, &As[c * 8]);
    }
    #pragma unroll
    for (int ii = 0; ii < 4; ++ii) {  // B: 2048 chunks
      const int c = tid + ii * 512;
      const int r = c >> 3, s2 = (c & 7) ^ (r & 7);
      gload_lds16(Wb + (size_t)(col0 + r) * 1024 + kt * 64 + s2 * 8, &Bs[c * 8]);
    }
    __syncthreads();   // vmcnt(0) drain + barrier

    #pragma unroll
    for (int kk = 0; kk < 2; ++kk) {
      const uint32_t ksl = (uint32_t)((kk * 4 + g) << 4);
      s16x8 af[4], bf[4];
      #pragma unroll
      for (int t = 0; t < 4; ++t) {
        af[t] = *reinterpret_cast<const s16x8*>(
            reinterpret_cast<const char*>(As) + arow[t] + (ksl ^ asw[t]));
        bf[t] = *reinterpret_cast<const s16x8*>(
            reinterpret_cast<const char*>(Bs) + brow[t] + (ksl ^ bsw[t]));
      }
      #pragma unroll
      for (int a = 0; a < 4; ++a)
        #pragma unroll
        for (int b = 0; b < 4; ++b)
          acc[a][b] = __builtin_amdgcn_mfma_f32_16x16x32_bf16(af[a], bf[b], acc[a][b], 0, 0, 0);
    }
  }

  // epilogue: exp(S + bias), write P bf16, per-row denom atomics
  float biasv[4];
  #pragma unroll
  for (int b = 0; b < 4; ++b) {
    const int v = col0 + nw * 64 + b * 16 + r16;
    biasv[b] = (v < VOCAB) ? bias[v] : 0.f;
  }
  #pragma unroll
  for (int a = 0; a < 4; ++a) {
    #pragma unroll
    for (int j = 0; j < 4; ++j) {
      const int q = row0 + mw * 64 + a * 16 + g * 4 + j;
      float rsum = 0.f;
      #pragma unroll
      for (int b = 0; b < 4; ++b) {
        const int v = col0 + nw * 64 + b * 16 + r16;
        float e = (v < VOCAB) ? __expf(acc[a][b][j] + biasv[b]) : 0.f;
        rsum += e;
        P[(size_t)q * VP + v] = f2bf(e);
      }
      rsum += __shfl_xor(rsum, 1);
      rsum += __shfl_xor(rsum, 2);
      rsum += __shfl_xor(rsum, 4);
      rsum += __shfl_xor(rsum, 8);
      if (r16 == 0) atomicAdd(&den[(size_t)q * 8 + (nt_ & 7)], rsum);
    }
  }
}

// ---- GEMM2: opart[ks] = P.ET^T slice, K-split 8 over VP ----
// 256(q) x 128(d) tile, BK=64, 8 waves (4m x 2n), wave 64x64, 100 K-steps.
// Block order: d-tile FAST -> 8 consecutive blocks share one 3.3 MB P-slab (L2-hit).
__global__ __launch_bounds__(512, 4)
void k_gemm2(const unsigned short* __restrict__ P,
             const unsigned short* __restrict__ ET,
             float* __restrict__ opart) {
  __shared__ __align__(16) unsigned short As[256 * 64];  // 32 KB P rows
  __shared__ __align__(16) unsigned short Bs[128 * 64];  // 16 KB ET rows

  const int bx = blockIdx.x;
  const int ks = bx & 7, bi = bx >> 3;       // XCD owns one K-split; bi in [0,128)
  const int nd = bi & 7, mt_ = bi >> 3;      // d-tile FAST (P-slab L2 reuse)
  const int row0 = mt_ * 256, col0 = nd * 128;
  const int k0 = ks * (VP / 8);              // 6400

  const int tid = threadIdx.x;
  const int w = tid >> 6, l = tid & 63;
  const int mw = w >> 1, nw = w & 1;
  const int r16 = l & 15, g = l >> 4;

  f32x4 acc[4][4];
  #pragma unroll
  for (int a = 0; a < 4; ++a)
    #pragma unroll
    for (int b = 0; b < 4; ++b) acc[a][b] = f32x4{0.f, 0.f, 0.f, 0.f};

  uint32_t arow[4], asw[4], brow[4], bsw[4];
  #pragma unroll
  for (int t = 0; t < 4; ++t) {
    const uint32_t ar = mw * 64 + t * 16 + r16;
    arow[t] = ar * 128; asw[t] = (ar & 7) << 4;
    const uint32_t br = nw * 64 + t * 16 + r16;
    brow[t] = br * 128; bsw[t] = (br & 7) << 4;
  }

  for (int kt = 0; kt < 100; ++kt) {
    const int koff = k0 + kt * 64;
    __syncthreads();
    #pragma unroll
    for (int ii = 0; ii < 4; ++ii) {  // A: 2048 chunks
      const int c = tid + ii * 512;
      const int r = c >> 3, s2 = (c & 7) ^ (r & 7);
      gload_lds16(P + (size_t)(row0 + r) * VP + koff + s2 * 8, &As[c * 8]);
    }
    #pragma unroll
    for (int ii = 0; ii < 2; ++ii) {  // B: 1024 chunks
      const int c = tid + ii * 512;
      const int r = c >> 3, s2 = (c & 7) ^ (r & 7);
      gload_lds16(ET + (size_t)(col0 + r) * VP + koff + s2 * 8, &Bs[c * 8]);
    }
    __syncthreads();

    #pragma unroll
    for (int kk = 0; kk < 2; ++kk) {
      const uint32_t ksl = (uint32_t)((kk * 4 + g) << 4);
      s16x8 af[4], bf[4];
      #pragma unroll
      for (int t = 0; t < 4; ++t) {
        af[t] = *reinterpret_cast<const s16x8*>(
            reinterpret_cast<const char*>(As) + arow[t] + (ksl ^ asw[t]));
        bf[t] = *reinterpret_cast<const s16x8*>(
            reinterpret_cast<const char*>(Bs) + brow[t] + (ksl ^ bsw[t]));
      }
      #pragma unroll
      for (int a = 0; a < 4; ++a)
        #pragma unroll
        for (int b = 0; b < 4; ++b)
          acc[a][b] = __builtin_amdgcn_mfma_f32_16x16x32_bf16(af[a], bf[b], acc[a][b], 0, 0, 0);
    }
  }

  // epilogue: write f32 partial [ks][q][d]
  #pragma unroll
  for (int a = 0; a < 4; ++a) {
    #pragma unroll
    for (int j = 0; j < 4; ++j) {
      const int q = row0 + mw * 64 + a * 16 + g * 4 + j;
      float* orow = opart + ((size_t)ks * ROWS + q) * D_MODEL;
      #pragma unroll
      for (int b = 0; b < 4; ++b) {
        const int d = col0 + nw * 64 + b * 16 + r16;
        orow[d] = acc[a][b][j];
      }
    }
  }
}

// ---- LN epilogue: combine 8 partials + den, residual, LayerNorm ----
__global__ __launch_bounds__(256)
void k_ln2(const float* __restrict__ enc, const float* __restrict__ opart,
           const float* __restrict__ den, const float* __restrict__ gam,
           const float* __restrict__ bet, float* __restrict__ out) {
  __shared__ float r1[4], r2[4];
  const int row = blockIdx.x;
  const int t = threadIdx.x;
  const int d = t * 4;
  float dn = 0.f;
  #pragma unroll
  for (int s = 0; s < 8; ++s) dn += den[(size_t)row * 8 + s];
  const float inv = 1.f / dn;
  f32x4 acc = {0.f, 0.f, 0.f, 0.f};
  #pragma unroll
  for (int ks = 0; ks < 8; ++ks) {
    const f32x4 a = *reinterpret_cast<const f32x4*>(opart + ((size_t)ks * ROWS + row) * D_MODEL + d);
    #pragma unroll
    for (int jj = 0; jj < 4; ++jj) acc[jj] += a[jj];
  }
  const f32x4 e = *reinterpret_cast<const f32x4*>(enc + (size_t)row * D_MODEL + d);
  f32x4 y;
  #pragma unroll
  for (int jj = 0; jj < 4; ++jj) y[jj] = e[jj] + acc[jj] * inv;
  float s1 = y[0] + y[1] + y[2] + y[3];
  float s2 = y[0]*y[0] + y[1]*y[1] + y[2]*y[2] + y[3]*y[3];
  #pragma unroll
  for (int off = 1; off < 64; off <<= 1) {
    s1 += __shfl_xor(s1, off);
    s2 += __shfl_xor(s2, off);
  }
  if ((t & 63) == 0) { r1[t >> 6] = s1; r2[t >> 6] = s2; }
  __syncthreads();
  const float S1 = r1[0] + r1[1] + r1[2] + r1[3];
  const float S2 = r2[0] + r2[1] + r2[2] + r2[3];
  const float mean = S1 * (1.f / D_MODEL);
  const float var = S2 * (1.f / D_MODEL) - mean * mean;
  const float rs = rsqrtf(var + LN_EPS);
  const f32x4 gv = *reinterpret_cast<const f32x4*>(gam + d);
  const f32x4 bv = *reinterpret_cast<const f32x4*>(bet + d);
  f32x4 o;
  #pragma unroll
  for (int jj = 0; jj < 4; ++jj) o[jj] = (y[jj] - mean) * rs * gv[jj] + bv[jj];
  *reinterpret_cast<f32x4*>(out + (size_t)row * D_MODEL + d) = o;
}

// ============================================================================
extern "C" void kernel_launch(void* const* d_in, const int* in_sizes, int n_in,
                              void* d_out, int out_size, void* d_ws, size_t ws_size,
                              hipStream_t stream) {
  const float* enc = (const float*)d_in[0];
  const float* pw  = (const float*)d_in[1];
  const float* pb  = (const float*)d_in[2];
  const float* emb = (const float*)d_in[3];
  const float* gam = (const float*)d_in[4];
  const float* bet = (const float*)d_in[5];
  float* out = (float*)d_out;

  size_t off = 0;
  unsigned short* encb = (unsigned short*)((char*)d_ws + off); off += (size_t)ROWS * D_MODEL * 2;
  unsigned short* Wb   = (unsigned short*)((char*)d_ws + off); off += (size_t)VP * D_MODEL * 2;
  unsigned short* ET   = (unsigned short*)((char*)d_ws + off); off += (size_t)D_MODEL * VP * 2;
  unsigned short* P    = (unsigned short*)((char*)d_ws + off); off += (size_t)ROWS * VP * 2;
  float* opart         = (float*)((char*)d_ws + off);          off += (size_t)8 * ROWS * D_MODEL * 4;
  float* den           = (float*)((char*)d_ws + off);          off += (size_t)ROWS * 8 * 4;

  if (off > ws_size) {
    // unambiguous sentinel: ws too small -> absmax ~3.4e38
    hipMemsetAsync(d_out, 0x7f, (size_t)out_size * 4, stream);
    return;
  }

  hipMemsetAsync(den, 0, (size_t)ROWS * 8 * 4, stream);
  k_cast_enc<<<(ROWS * D_MODEL / 8) / 256, 256, 0, stream>>>(enc, encb);
  k_pack_wlin<<<((size_t)VP * D_MODEL / 8) / 256, 256, 0, stream>>>(pw, Wb);
  k_pack_et<<<dim3(VP / 32, D_MODEL / 32), dim3(32, 8), 0, stream>>>(emb, ET);
  k_gemm1<<<6400, 512, 0, stream>>>(encb, Wb, pb, P, den);
  k_gemm2<<<1024, 512, 0, stream>>>(P, ET, opart);
  k_ln2<<<ROWS, 256, 0, stream>>>(enc, opart, den, gam, bet, out);
}